// Round 7
// baseline (344.717 us; speedup 1.0000x reference)
//
#include <hip/hip_runtime.h>
#include <hip/hip_bf16.h>
#include <stdint.h>

// B=2, S=2048, D=1024, H=16, HD=64.  M = B*S = 4096.
// R7: cvt folded into reg-staged GEMMs (no separate cvt dispatch); all kernels
// use raw barriers with counted/no vmcnt drains; attn at 128-thr blocks (4/CU).

#define LOG2E 1.4426950408889634f
#define LGKM0 asm volatile("s_waitcnt lgkmcnt(0)" ::: "memory")
#define SCHED0 __builtin_amdgcn_sched_barrier(0)
#define BAR __builtin_amdgcn_s_barrier()

typedef __bf16 bf16x8 __attribute__((ext_vector_type(8)));
typedef float f32x4 __attribute__((ext_vector_type(4)));

__device__ __forceinline__ ushort f2bf(float f) {
  union { float f; uint32_t u; } v; v.f = f;
  uint32_t u = v.u + 0x7FFFu + ((v.u >> 16) & 1u);
  return (ushort)(u >> 16);
}
// truncating bf16 pair-pack (inputs ~N(0,1): quant err <= 2^-8 rel, within budget)
__device__ __forceinline__ uint32_t pack2t(float a, float b) {
  uint32_t ua = __builtin_bit_cast(uint32_t, a);
  uint32_t ub = __builtin_bit_cast(uint32_t, b);
  return (ua >> 16) | (ub & 0xFFFF0000u);
}
__device__ __forceinline__ bf16x8 ld_frag(const ushort* p) {
  return __builtin_bit_cast(bf16x8, *(const uint4*)p);
}
__device__ __forceinline__ void gl_lds16(const void* g, void* l) {
  __builtin_amdgcn_global_load_lds(
      (const __attribute__((address_space(1))) void*)g,
      (__attribute__((address_space(3))) void*)l, 16, 0, 0);
}

// swizzled LDS index: row-major pitch 64 elems, 16B granule XOR'd by row&7
__device__ __forceinline__ int swz(int row, int gran) {
  return row * 64 + ((gran ^ (row & 7)) << 3);
}

// gl_lds staging of ROWS x 64 bf16 tile with NW waves; swizzle pre-applied on
// the per-lane global source (LDS dest linear). (attn K tiles)
template <int ROWS, int NW>
__device__ __forceinline__ void stage_tile(const ushort* src, int stride,
                                           ushort* dst, int wid, int lane) {
  const int rloc = lane >> 3;
  const int gsrc = (lane & 7) ^ (rloc & 7);
  constexpr int RW = ROWS / NW;
  const ushort* s = src + (size_t)(wid * RW + rloc) * stride + gsrc * 8;
#pragma unroll
  for (int j = 0; j < RW / 8; ++j)
    gl_lds16(s + (size_t)(j * 8) * stride, dst + (wid * RW + j * 8) * 64);
}

// ---- reg-staged tile loaders (256-thread blocks), fp32->bf16 or bf16 ----
template <int ROWS>
struct StF32 {  // ROWS x 64 fp32 -> bf16 LDS (truncating convert)
  static constexpr int TPR = 256 / ROWS, CPT = 64 / TPR, NL = CPT / 4, NG = CPT / 8;
  float4 f[NL];
  __device__ __forceinline__ void load(const float* base, int Kdim, int tid, int k0) {
    const int row = tid / TPR, part = tid % TPR;
    const float* p = base + (size_t)row * Kdim + k0 + part * CPT;
#pragma unroll
    for (int j = 0; j < NL; ++j) f[j] = ((const float4*)p)[j];
  }
  __device__ __forceinline__ void store(ushort* dst, int tid) {
    const int row = tid / TPR, part = tid % TPR;
#pragma unroll
    for (int g = 0; g < NG; ++g) {
      uint4 h;
      h.x = pack2t(f[2 * g].x, f[2 * g].y);
      h.y = pack2t(f[2 * g].z, f[2 * g].w);
      h.z = pack2t(f[2 * g + 1].x, f[2 * g + 1].y);
      h.w = pack2t(f[2 * g + 1].z, f[2 * g + 1].w);
      *(uint4*)&dst[swz(row, part * NG + g)] = h;
    }
  }
};
template <int ROWS>
struct StB16 {  // ROWS x 64 bf16 -> bf16 LDS
  static constexpr int TPR = 256 / ROWS, CPT = 64 / TPR, NG = CPT / 8;
  uint4 u[NG];
  __device__ __forceinline__ void load(const ushort* base, int Kdim, int tid, int k0) {
    const int row = tid / TPR, part = tid % TPR;
    const ushort* p = base + (size_t)row * Kdim + k0 + part * CPT;
#pragma unroll
    for (int g = 0; g < NG; ++g) u[g] = ((const uint4*)p)[g];
  }
  __device__ __forceinline__ void store(ushort* dst, int tid) {
    const int row = tid / TPR, part = tid % TPR;
#pragma unroll
    for (int g = 0; g < NG; ++g) *(uint4*)&dst[swz(row, part * NG + g)] = u[g];
  }
};

// ---------------------------------------------------------------------------
// GEMM: Y[m][n] = sum_k A[m][k] * W[n][k] + bias[n]
// A: fp32 (converted in staging) or bf16; W: fp32 (converted); Y: bf16 or f32.
// BM=128, BN=128|64, BK=64, 256 thr (2x2 waves, 64x(BN/2) per wave).
// One-barrier K-loop: compute(t) || loads(t+1) in regs -> write buf^1 -> issue
// loads(t+2) -> lgkm0+barrier. No vmcnt(0) drains anywhere.
// ---------------------------------------------------------------------------
template <int BN, int NX, bool A_BF16, bool OUT_BF16, bool PROJ3>
__global__ __launch_bounds__(256, 2) void gemm_rs(
    const void* __restrict__ A0, const void* __restrict__ A1, const void* __restrict__ A2,
    const float* __restrict__ W0, const float* __restrict__ W1, const float* __restrict__ W2,
    const float* __restrict__ b0, const float* __restrict__ b1, const float* __restrict__ b2,
    void* __restrict__ Y0, void* __restrict__ Y1, void* __restrict__ Y2,
    int Ndim, int Kdim) {
  __shared__ ushort Al[2][128 * 64];
  __shared__ ushort Bl[2][BN * 64];

  const int z = PROJ3 ? blockIdx.y : 0;
  const void* Ap = (z == 0) ? A0 : (z == 1) ? A1 : A2;
  const float* W = (z == 0) ? W0 : (z == 1) ? W1 : W2;
  const float* bias = (z == 0) ? b0 : (z == 1) ? b1 : b2;
  void* Yp = (z == 0) ? Y0 : (z == 1) ? Y1 : Y2;

  // XCD-chunked remap (null so far, zero-cost; keep)
  const int id = blockIdx.x;
  const int xcd = id & 7;
  const int slot = id >> 3;
  const int by = xcd * 4 + (slot & 3);
  const int bx = slot >> 2;

  const int tid = threadIdx.x;
  const int wid = tid >> 6, lane = tid & 63;
  const int row0 = by * 128, col0 = bx * BN;
  const int wr = wid >> 1, wc = wid & 1;
  const int lr = lane & 15, lg = lane >> 4;
  constexpr int NF = BN / 32;

  const float* Af = (const float*)Ap + (size_t)row0 * Kdim;
  const ushort* Ab = (const ushort*)Ap + (size_t)row0 * Kdim;
  const float* Wrow = W + (size_t)col0 * Kdim;

  StF32<128> af32; StB16<128> ab16; StF32<BN> ws;
  f32x4 acc[4][NF] = {};

  // prologue: tile 0 staged, tile 1 loads in flight
  if (A_BF16) { ab16.load(Ab, Kdim, tid, 0); } else { af32.load(Af, Kdim, tid, 0); }
  ws.load(Wrow, Kdim, tid, 0);
  if (A_BF16) { ab16.store(Al[0], tid); } else { af32.store(Al[0], tid); }
  ws.store(Bl[0], tid);
  if (A_BF16) { ab16.load(Ab, Kdim, tid, 64); } else { af32.load(Af, Kdim, tid, 64); }
  ws.load(Wrow, Kdim, tid, 64);
  LGKM0; SCHED0; BAR;

  const int NT = Kdim >> 6;
  int cur = 0;
#pragma unroll 1
  for (int t = 0; t < NT; ++t) {
    const ushort* Ac = Al[cur];
    const ushort* Bc = Bl[cur];
#pragma unroll
    for (int kk = 0; kk < 2; ++kk) {
      bf16x8 afr[4], bfr[NF];
#pragma unroll
      for (int m = 0; m < 4; ++m)
        afr[m] = ld_frag(&Ac[swz(wr * 64 + m * 16 + lr, kk * 4 + lg)]);
#pragma unroll
      for (int n = 0; n < NF; ++n)
        bfr[n] = ld_frag(&Bc[swz(wc * (BN / 2) + n * 16 + lr, kk * 4 + lg)]);
#pragma unroll
      for (int m = 0; m < 4; ++m)
#pragma unroll
        for (int n = 0; n < NF; ++n)
          acc[m][n] = __builtin_amdgcn_mfma_f32_16x16x32_bf16(afr[m], bfr[n], acc[m][n], 0, 0, 0);
    }
    if (t + 1 < NT) {
      // write tile t+1 (regs loaded one iter ago; auto-vmcnt waits here, hidden)
      if (A_BF16) { ab16.store(Al[cur ^ 1], tid); } else { af32.store(Al[cur ^ 1], tid); }
      ws.store(Bl[cur ^ 1], tid);
      if (t + 2 < NT) {  // issue loads for t+2; stay in flight across barrier
        if (A_BF16) { ab16.load(Ab, Kdim, tid, (t + 2) * 64); }
        else { af32.load(Af, Kdim, tid, (t + 2) * 64); }
        ws.load(Wrow, Kdim, tid, (t + 2) * 64);
      }
    }
    LGKM0; SCHED0; BAR;
    cur ^= 1;
  }

#pragma unroll
  for (int n = 0; n < NF; ++n) {
    int col = col0 + wc * (BN / 2) + n * 16 + lr;
    float bv = bias[col];
#pragma unroll
    for (int m = 0; m < 4; ++m) {
#pragma unroll
      for (int r = 0; r < 4; ++r) {
        int row = row0 + wr * 64 + m * 16 + lg * 4 + r;
        float v = acc[m][n][r] + bv;
        if (OUT_BF16)
          ((ushort*)Yp)[(size_t)row * Ndim + col] = f2bf(v);
        else
          ((float*)Yp)[(size_t)row * Ndim + col] = v;
      }
    }
  }
}

// ---------------------------------------------------------------------------
// Flash attention, causal. Block = 32 q-rows (2 waves), pair (qi, 63-qi)
// processed sequentially -> uniform 33 KV-tiles/block; 1024 blocks (~4/CU).
// Raw barriers only: SYNC1 = lgkm0+bar (Vt/P visibility; K gl_lds covered by
// in-order vmcnt via va/vb dependency), SYNC2 = plain bar (no drains).
// ---------------------------------------------------------------------------
__global__ __launch_bounds__(128, 2) void attn_kernel(
    const ushort* __restrict__ Qb, const ushort* __restrict__ Kb,
    const ushort* __restrict__ Vb, ushort* __restrict__ Cx) {
  __shared__ ushort Kl[2][64 * 64];
  __shared__ ushort Vt[64 * 64];     // V^T tile: row=hd, col=kv (swizzled)
  __shared__ ushort Pl[2][16 * 64];  // per-wave P [q][kv] (swizzled)

  const int tid = threadIdx.x;
  const int wid = tid >> 6, lane = tid & 63;
  const int lr = lane & 15, lg = lane >> 4;
  const int x = blockIdx.x;  // bh
  const int p = blockIdx.y;  // pair 0..31
  const int b = x >> 4, h = x & 15;
  const size_t base = (size_t)b * 2048 * 1024 + h * 64;
  const float SCL = 0.125f * LOG2E;
  const int vp = tid & 31;   // kv-pair 0..31
  const int c0 = tid >> 5;   // hd-chunk 0..3 (covers c0 and c0+4)

#pragma unroll 1
  for (int seg = 0; seg < 2; ++seg) {
    const int qi = seg ? (63 - p) : p;       // 32-row q-tile index 0..63
    const int qb0 = qi * 32;
    const int q0w = qb0 + wid * 16;
    const int nt = (qi >> 1) + 1;            // pairs sum to 33

    bf16x8 qf[2];
    {
      const ushort* qs = Qb + base + (size_t)(q0w + lr) * 1024 + lg * 8;
      qf[0] = ld_frag(qs);
      qf[1] = ld_frag(qs + 32);
    }

    f32x4 O[4] = {};
    float m_reg = -1e30f, l_reg = 0.f;

    stage_tile<64, 2>(Kb + base, 1024, Kl[0], wid, lane);
    uint4 va0 = *(const uint4*)(Vb + base + (size_t)(2 * vp) * 1024 + c0 * 8);
    uint4 vb0 = *(const uint4*)(Vb + base + (size_t)(2 * vp + 1) * 1024 + c0 * 8);
    uint4 va1 = *(const uint4*)(Vb + base + (size_t)(2 * vp) * 1024 + (c0 + 4) * 8);
    uint4 vb1 = *(const uint4*)(Vb + base + (size_t)(2 * vp + 1) * 1024 + (c0 + 4) * 8);

#pragma unroll 1
    for (int t = 0; t < nt; ++t) {
      const int kv0 = t * 64;
      {  // write V^T tile (b32 packed, swizzled; auto-vmcnt waits va/vb here,
         // which by in-order vmcnt also guarantees the older K gl_lds landed)
        const ushort* pA0 = (const ushort*)&va0;
        const ushort* pB0 = (const ushort*)&vb0;
        const ushort* pA1 = (const ushort*)&va1;
        const ushort* pB1 = (const ushort*)&vb1;
#pragma unroll
        for (int j = 0; j < 8; ++j) {
          int idx = (c0 * 8 + j) * 64 + (((vp >> 2) ^ j) << 3) + ((vp * 2) & 7);
          *(uint32_t*)&Vt[idx] = (uint32_t)pA0[j] | ((uint32_t)pB0[j] << 16);
        }
#pragma unroll
        for (int j = 0; j < 8; ++j) {
          int idx = ((c0 + 4) * 8 + j) * 64 + (((vp >> 2) ^ j) << 3) + ((vp * 2) & 7);
          *(uint32_t*)&Vt[idx] = (uint32_t)pA1[j] | ((uint32_t)pB1[j] << 16);
        }
      }
      LGKM0; SCHED0; BAR;  // SYNC1: Vt + Kl[t&1] visible to both waves

      if (t + 1 < nt) {  // prefetch t+1 (stays in flight across barriers)
        stage_tile<64, 2>(Kb + base + (size_t)(kv0 + 64) * 1024, 1024, Kl[(t + 1) & 1], wid, lane);
        va0 = *(const uint4*)(Vb + base + (size_t)(kv0 + 64 + 2 * vp) * 1024 + c0 * 8);
        vb0 = *(const uint4*)(Vb + base + (size_t)(kv0 + 64 + 2 * vp + 1) * 1024 + c0 * 8);
        va1 = *(const uint4*)(Vb + base + (size_t)(kv0 + 64 + 2 * vp) * 1024 + (c0 + 4) * 8);
        vb1 = *(const uint4*)(Vb + base + (size_t)(kv0 + 64 + 2 * vp + 1) * 1024 + (c0 + 4) * 8);
      }

      const bool dm = (t == nt - 1);
      const ushort* Kc = Kl[t & 1];

      // S^T = K Q^T : lane holds S[q=q0w+lr][kv=kv0+cb*16+lg*4+r]
      f32x4 st[4];
#pragma unroll
      for (int cb = 0; cb < 4; ++cb) {
        if (kv0 + cb * 16 > q0w + 15) {
          st[cb] = f32x4{-1e30f, -1e30f, -1e30f, -1e30f};
          continue;
        }
        f32x4 a = {};
#pragma unroll
        for (int kk = 0; kk < 2; ++kk) {
          bf16x8 kfrag = ld_frag(&Kc[swz(cb * 16 + lr, kk * 4 + lg)]);
          a = __builtin_amdgcn_mfma_f32_16x16x32_bf16(kfrag, qf[kk], a, 0, 0, 0);
        }
#pragma unroll
        for (int r = 0; r < 4; ++r) {
          float sv = a[r] * SCL;
          if (dm) {
            int kv = kv0 + cb * 16 + lg * 4 + r;
            if (kv > q0w + lr) sv = -1e30f;
          }
          a[r] = sv;
        }
        st[cb] = a;
      }

      // per-lane online softmax (q=lr; reduce across lg via xor 16/32)
      float tmax = -1e30f;
#pragma unroll
      for (int cb = 0; cb < 4; ++cb) {
        float c01 = fmaxf(st[cb][0], st[cb][1]);
        float c23 = fmaxf(st[cb][2], st[cb][3]);
        tmax = fmaxf(tmax, fmaxf(c01, c23));
      }
      tmax = fmaxf(tmax, __shfl_xor(tmax, 16));
      tmax = fmaxf(tmax, __shfl_xor(tmax, 32));

      const bool skip = __all(tmax - m_reg <= 8.f);
      float mcur;
      if (skip) {
        mcur = m_reg;
      } else {
        mcur = fmaxf(m_reg, tmax);
        float alpha = exp2f(m_reg - mcur);
        m_reg = mcur;
        l_reg *= alpha;
        float aO[4];
#pragma unroll
        for (int r = 0; r < 4; ++r)
          aO[r] = __shfl(alpha, (lane & 48) | ((lane >> 2) & 12) | r);
#pragma unroll
        for (int n = 0; n < 4; ++n)
#pragma unroll
          for (int r = 0; r < 4; ++r) O[n][r] *= aO[r];
      }

      float ts = 0.f;
#pragma unroll
      for (int cb = 0; cb < 4; ++cb)
#pragma unroll
        for (int r = 0; r < 4; ++r) {
          float pv = exp2f(st[cb][r] - mcur);
          st[cb][r] = pv;
          ts += pv;
        }
      ts += __shfl_xor(ts, 16);
      ts += __shfl_xor(ts, 32);
      l_reg += ts;

      // P^T regs -> Pl[wid] as P[q=lr][kv] (b32 trunc-packed, swizzled)
      ushort* pw = &Pl[wid][0];
#pragma unroll
      for (int cb = 0; cb < 4; ++cb) {
        int g = ((cb * 2 + (lg >> 1)) ^ (lr & 7)) << 3;
        int idx = lr * 64 + g + ((lg & 1) * 4);
        *(uint32_t*)&pw[idx] = pack2t(st[cb][0], st[cb][1]);
        *(uint32_t*)&pw[idx + 2] = pack2t(st[cb][2], st[cb][3]);
      }
      // same-wave DS write->read ordered by compiler

      // O += P V
#pragma unroll
      for (int kk = 0; kk < 2; ++kk) {
        bf16x8 pa = ld_frag(&pw[swz(lr, kk * 4 + lg)]);
#pragma unroll
        for (int n = 0; n < 4; ++n) {
          bf16x8 vfr = ld_frag(&Vt[swz(n * 16 + lr, kk * 4 + lg)]);
          O[n] = __builtin_amdgcn_mfma_f32_16x16x32_bf16(pa, vfr, O[n], 0, 0, 0);
        }
      }
      BAR;  // SYNC2: exec-only; protect Vt/Pl/Kl reuse (no vmcnt drain)
    }

    // epilogue: normalize, write ctx rows
#pragma unroll
    for (int r = 0; r < 4; ++r) {
      float ls = __shfl(l_reg, (lane & 48) | ((lane >> 2) & 12) | r);
      float inv = 1.f / ls;
      size_t row = (size_t)b * 2048 + q0w + lg * 4 + r;
#pragma unroll
      for (int n = 0; n < 4; ++n)
        Cx[row * 1024 + h * 64 + n * 16 + lr] = f2bf(O[n][r] * inv);
    }
  }
}

// ---------------------------------------------------------------------------
extern "C" void kernel_launch(void* const* d_in, const int* in_sizes, int n_in,
                              void* d_out, int out_size, void* d_ws, size_t ws_size,
                              hipStream_t stream) {
  const float* query = (const float*)d_in[0];
  const float* key_i = (const float*)d_in[1];
  const float* value = (const float*)d_in[2];
  // d_in[3] = mask: known causal (tril), exploited structurally.
  const float* Wq = (const float*)d_in[4];
  const float* bq = (const float*)d_in[5];
  const float* Wk = (const float*)d_in[6];
  const float* bk = (const float*)d_in[7];
  const float* Wv = (const float*)d_in[8];
  const float* bv = (const float*)d_in[9];
  const float* Wo = (const float*)d_in[10];
  const float* bo = (const float*)d_in[11];
  float* out = (float*)d_out;

  const size_t MD = (size_t)4096 * 1024;
  ushort* Qb = (ushort*)d_ws;
  ushort* Kb = Qb + MD;
  ushort* Vb = Kb + MD;
  ushort* Cx = Vb + MD;

  // fused q/k/v projections: fp32 in (cvt folded into staging), bf16 out
  gemm_rs<128, 8, false, true, true><<<dim3(256, 3), 256, 0, stream>>>(
      query, key_i, value, Wq, Wk, Wv, bq, bk, bv, Qb, Kb, Vb, 1024, 1024);

  // attention: 32 bh x 32 pairs = 1024 uniform blocks, 128 thr (~4/CU)
  attn_kernel<<<dim3(32, 32), 128, 0, stream>>>(Qb, Kb, Vb, Cx);

  // out projection: bf16 A (attn out), fp32 W folded-cvt, fp32 out
  gemm_rs<64, 16, true, false, false><<<dim3(512, 1), 256, 0, stream>>>(
      Cx, Cx, Cx, Wo, Wo, Wo, bo, bo, bo, out, out, out, 1024, 1024);
}

// Round 8
// 275.576 us; speedup vs baseline: 1.2509x; 1.2509x over previous
//
#include <hip/hip_runtime.h>
#include <hip/hip_bf16.h>
#include <stdint.h>

// B=2, S=2048, D=1024, H=16, HD=64.  M = B*S = 4096.
// R8: concurrency round. cvt -> 8-wave single-buffer gl_lds GEMMs (24 waves/CU)
// -> kv-parity-split flash attn (16 waves/CU) -> 8-wave out GEMM.

#define LOG2E 1.4426950408889634f
#define BAR __builtin_amdgcn_s_barrier()

typedef __bf16 bf16x8 __attribute__((ext_vector_type(8)));
typedef float f32x4 __attribute__((ext_vector_type(4)));

__device__ __forceinline__ ushort f2bf(float f) {
  union { float f; uint32_t u; } v; v.f = f;
  uint32_t u = v.u + 0x7FFFu + ((v.u >> 16) & 1u);
  return (ushort)(u >> 16);
}
__device__ __forceinline__ uint32_t pack2(float a, float b) {
  return (uint32_t)f2bf(a) | ((uint32_t)f2bf(b) << 16);
}
// truncating bf16 pair-pack for P in [0,256]
__device__ __forceinline__ uint32_t pack2t(float a, float b) {
  uint32_t ua = __builtin_bit_cast(uint32_t, a);
  uint32_t ub = __builtin_bit_cast(uint32_t, b);
  return (ua >> 16) | (ub & 0xFFFF0000u);
}
__device__ __forceinline__ bf16x8 ld_frag(const ushort* p) {
  return __builtin_bit_cast(bf16x8, *(const uint4*)p);
}
__device__ __forceinline__ void gl_lds16(const void* g, void* l) {
  __builtin_amdgcn_global_load_lds(
      (const __attribute__((address_space(1))) void*)g,
      (__attribute__((address_space(3))) void*)l, 16, 0, 0);
}

// swizzled LDS index: row-major pitch 64 elems, 16B granule XOR'd by row&7
__device__ __forceinline__ int swz(int row, int gran) {
  return row * 64 + ((gran ^ (row & 7)) << 3);
}

// gl_lds staging of ROWS x 64 bf16 tile by NW waves; swizzle pre-applied on the
// per-lane GLOBAL source (LDS dest linear).
template <int ROWS, int NW>
__device__ __forceinline__ void stage_tile(const ushort* src, int stride,
                                           ushort* dst, int wid, int lane) {
  const int rloc = lane >> 3;
  const int gsrc = (lane & 7) ^ (rloc & 7);
  constexpr int RW = ROWS / NW;
  const ushort* s = src + (size_t)(wid * RW + rloc) * stride + gsrc * 8;
#pragma unroll
  for (int j = 0; j < RW / 8; ++j)
    gl_lds16(s + (size_t)(j * 8) * stride, dst + (wid * RW + j * 8) * 64);
}

// ---------------------------------------------------------------------------
// fp32 -> bf16 convert: flat grid-stride over 3x4M inputs + 4x1M weights.
// ---------------------------------------------------------------------------
__global__ void cvt_all(const float* __restrict__ s0, const float* __restrict__ s1,
                        const float* __restrict__ s2, const float* __restrict__ s3,
                        const float* __restrict__ s4, const float* __restrict__ s5,
                        const float* __restrict__ s6, ushort* __restrict__ d0,
                        ushort* __restrict__ d1, ushort* __restrict__ d2,
                        ushort* __restrict__ d3, ushort* __restrict__ d4,
                        ushort* __restrict__ d5, ushort* __restrict__ d6) {
  const int M4 = 4096 * 1024, M1 = 1024 * 1024;
  const int total = (3 * M4 + 4 * M1) / 8;
  for (int u = blockIdx.x * 256 + threadIdx.x; u < total; u += gridDim.x * 256) {
    int i = u * 8;
    const float* s; ushort* d; int off;
    if (i < 3 * M4) {
      int y = i / M4; off = i - y * M4;
      s = (y == 0) ? s0 : (y == 1) ? s1 : s2;
      d = (y == 0) ? d0 : (y == 1) ? d1 : d2;
    } else {
      int j = i - 3 * M4;
      int y = j / M1; off = j - y * M1;
      s = (y == 0) ? s3 : (y == 1) ? s4 : (y == 2) ? s5 : s6;
      d = (y == 0) ? d3 : (y == 1) ? d4 : (y == 2) ? d5 : d6;
    }
    float4 f0 = ((const float4*)(s + off))[0];
    float4 f1 = ((const float4*)(s + off))[1];
    uint4 h;
    h.x = pack2(f0.x, f0.y); h.y = pack2(f0.z, f0.w);
    h.z = pack2(f1.x, f1.y); h.w = pack2(f1.z, f1.w);
    *(uint4*)(d + off) = h;
  }
}

// ---------------------------------------------------------------------------
// GEMM: Y[m][n] = sum_k A[m][k]*W[n][k] + bias[n]  (bf16 in, bf16/f32 out)
// BM=128, BN=128|64, BK=64; 512 threads = 8 waves (2 row x 4 col).
// Single-buffer LDS (32/24KB), gl_lds staging, 2 barriers/K-step (m97 pattern).
// Occupancy-first: proj3 768 blocks -> 3/CU = 24 waves/CU.
// ---------------------------------------------------------------------------
template <int BN, bool OUT_BF16, bool PROJ3>
__global__ __launch_bounds__(512, 2) void gemm8(
    const ushort* __restrict__ A0, const ushort* __restrict__ A1, const ushort* __restrict__ A2,
    const ushort* __restrict__ W0, const ushort* __restrict__ W1, const ushort* __restrict__ W2,
    const float* __restrict__ b0, const float* __restrict__ b1, const float* __restrict__ b2,
    void* __restrict__ Y0, void* __restrict__ Y1, void* __restrict__ Y2,
    int Ndim, int Kdim) {
  __shared__ ushort Al[128 * 64];
  __shared__ ushort Bl[BN * 64];

  const int z = PROJ3 ? blockIdx.z : 0;
  const ushort* A = (z == 0) ? A0 : (z == 1) ? A1 : A2;
  const ushort* W = (z == 0) ? W0 : (z == 1) ? W1 : W2;
  const float* bias = (z == 0) ? b0 : (z == 1) ? b1 : b2;
  void* Yp = (z == 0) ? Y0 : (z == 1) ? Y1 : Y2;

  const int tid = threadIdx.x;
  const int wid = tid >> 6, lane = tid & 63;
  const int row0 = blockIdx.y * 128, col0 = blockIdx.x * BN;
  const int wr = wid >> 2, wc = wid & 3;        // 2 x 4 waves
  const int lr = lane & 15, lg = lane >> 4;
  constexpr int NF = BN / 64;                   // frags per wave: 2 | 1
  constexpr int WC = BN / 4;                    // cols per wave: 32 | 16

  const ushort* Arow = A + (size_t)row0 * Kdim;
  const ushort* Wrow = W + (size_t)col0 * Kdim;

  f32x4 acc[4][NF] = {};

  const int NT = Kdim >> 6;
#pragma unroll 1
  for (int t = 0; t < NT; ++t) {
    stage_tile<128, 8>(Arow + t * 64, Kdim, Al, wid, lane);
    stage_tile<BN, 8>(Wrow + t * 64, Kdim, Bl, wid, lane);
    __syncthreads();
#pragma unroll
    for (int kk = 0; kk < 2; ++kk) {
      bf16x8 af[4], bf[NF];
#pragma unroll
      for (int m = 0; m < 4; ++m)
        af[m] = ld_frag(&Al[swz(wr * 64 + m * 16 + lr, kk * 4 + lg)]);
#pragma unroll
      for (int n = 0; n < NF; ++n)
        bf[n] = ld_frag(&Bl[swz(wc * WC + n * 16 + lr, kk * 4 + lg)]);
#pragma unroll
      for (int m = 0; m < 4; ++m)
#pragma unroll
        for (int n = 0; n < NF; ++n)
          acc[m][n] = __builtin_amdgcn_mfma_f32_16x16x32_bf16(af[m], bf[n], acc[m][n], 0, 0, 0);
    }
    __syncthreads();
  }

#pragma unroll
  for (int n = 0; n < NF; ++n) {
    int col = col0 + wc * WC + n * 16 + lr;
    float bv = bias[col];
#pragma unroll
    for (int m = 0; m < 4; ++m) {
#pragma unroll
      for (int r = 0; r < 4; ++r) {
        int row = row0 + wr * 64 + m * 16 + lg * 4 + r;
        float v = acc[m][n][r] + bv;
        if (OUT_BF16)
          ((ushort*)Yp)[(size_t)row * Ndim + col] = f2bf(v);
        else
          ((float*)Yp)[(size_t)row * Ndim + col] = v;
      }
    }
  }
}

// ---------------------------------------------------------------------------
// Flash attention, causal, kv-parity split.
// Block = 32 q-rows (pair (qi,63-qi) sequential, uniform ~33 tiles).
// 4 waves: wq=wid&1 -> q 16-row subtile; wk=wid>>1 -> kv-tile parity.
// Each parity keeps independent online (m,l,O); merged once per segment.
// 1024 blocks x 40KB -> 4 blocks/CU = 16 waves/CU.
// ---------------------------------------------------------------------------
__global__ __launch_bounds__(256, 4) void attn_kernel(
    const ushort* __restrict__ Qb, const ushort* __restrict__ Kb,
    const ushort* __restrict__ Vb, ushort* __restrict__ Cx) {
  __shared__ ushort Kl[2][64 * 64];   // K dbuf (swizzled)
  __shared__ ushort Vt[2][64 * 64];   // V^T dbuf (swizzled)
  __shared__ ushort Pl[4][16 * 64];   // per-wave P (swizzled)

  const int tid = threadIdx.x;
  const int wid = tid >> 6, lane = tid & 63;
  const int wq = wid & 1, wk = wid >> 1;
  const int lr = lane & 15, lg = lane >> 4;
  const int x = blockIdx.x;  // bh
  const int p = blockIdx.y;  // pair 0..31
  const int b = x >> 4, h = x & 15;
  const size_t base = (size_t)b * 2048 * 1024 + h * 64;
  const float SCL = 0.125f * LOG2E;
  const int vp = tid & 31;   // kv-pair 0..31
  const int vc = tid >> 5;   // hd-chunk 0..7

#pragma unroll 1
  for (int seg = 0; seg < 2; ++seg) {
    const int qi = seg ? (63 - p) : p;       // 32-row q-tile 0..63
    const int qb0 = qi * 32;
    const int q0w = qb0 + wq * 16;
    const int nt = (qi >> 1) + 1;

    bf16x8 qf[2];
    {
      const ushort* qs = Qb + base + (size_t)(q0w + lr) * 1024 + lg * 8;
      qf[0] = ld_frag(qs);
      qf[1] = ld_frag(qs + 32);
    }

    f32x4 O[4] = {};
    float m_reg = -1e30f, l_reg = 0.f;  // per-lane, q = q0w + lr

    // prologue: issue K(0) gl_lds, then V(0) reg loads (vmcnt-ordered after K)
    stage_tile<64, 4>(Kb + base, 1024, Kl[0], wid, lane);
    uint4 va = *(const uint4*)(Vb + base + (size_t)(2 * vp) * 1024 + vc * 8);
    uint4 vb = *(const uint4*)(Vb + base + (size_t)(2 * vp + 1) * 1024 + vc * 8);

#pragma unroll 1
    for (int t = 0; t < nt; ++t) {
      const int kv0 = t * 64;
      {  // write V^T(t): auto vmcnt wait on va/vb  =>  K(t) (older) also landed
        const ushort* pA = (const ushort*)&va;
        const ushort* pB = (const ushort*)&vb;
        ushort* vt = Vt[t & 1];
#pragma unroll
        for (int j = 0; j < 8; ++j) {
          int idx = (vc * 8 + j) * 64 + (((vp >> 2) ^ j) << 3) + ((vp * 2) & 7);
          *(uint32_t*)&vt[idx] = (uint32_t)pA[j] | ((uint32_t)pB[j] << 16);
        }
      }
      __syncthreads();  // Kl[t&1], Vt[t&1] visible to all waves

      if (t + 1 < nt) {  // issue next tile: K gl_lds first, then V reg loads
        stage_tile<64, 4>(Kb + base + (size_t)(kv0 + 64) * 1024, 1024,
                          Kl[(t + 1) & 1], wid, lane);
        va = *(const uint4*)(Vb + base + (size_t)(kv0 + 64 + 2 * vp) * 1024 + vc * 8);
        vb = *(const uint4*)(Vb + base + (size_t)(kv0 + 64 + 2 * vp + 1) * 1024 + vc * 8);
      }

      if (wk == (t & 1)) {  // this parity computes tile t
        const bool dm = (t == nt - 1);
        const ushort* Kc = Kl[t & 1];

        f32x4 st[4];
#pragma unroll
        for (int cb = 0; cb < 4; ++cb) {
          if (kv0 + cb * 16 > q0w + 15) {
            st[cb] = f32x4{-1e30f, -1e30f, -1e30f, -1e30f};
            continue;
          }
          f32x4 a = {};
#pragma unroll
          for (int kk = 0; kk < 2; ++kk) {
            bf16x8 kfrag = ld_frag(&Kc[swz(cb * 16 + lr, kk * 4 + lg)]);
            a = __builtin_amdgcn_mfma_f32_16x16x32_bf16(kfrag, qf[kk], a, 0, 0, 0);
          }
#pragma unroll
          for (int r = 0; r < 4; ++r) {
            float sv = a[r] * SCL;
            if (dm) {
              int kv = kv0 + cb * 16 + lg * 4 + r;
              if (kv > q0w + lr) sv = -1e30f;
            }
            a[r] = sv;
          }
          st[cb] = a;
        }

        float tmax = -1e30f;
#pragma unroll
        for (int cb = 0; cb < 4; ++cb) {
          float c01 = fmaxf(st[cb][0], st[cb][1]);
          float c23 = fmaxf(st[cb][2], st[cb][3]);
          tmax = fmaxf(tmax, fmaxf(c01, c23));
        }
        tmax = fmaxf(tmax, __shfl_xor(tmax, 16));
        tmax = fmaxf(tmax, __shfl_xor(tmax, 32));

        const bool skip = __all(tmax - m_reg <= 8.f);
        float mcur;
        if (skip) {
          mcur = m_reg;
        } else {
          mcur = fmaxf(m_reg, tmax);
          float alpha = exp2f(m_reg - mcur);
          m_reg = mcur;
          l_reg *= alpha;
          float aO[4];
#pragma unroll
          for (int r = 0; r < 4; ++r)
            aO[r] = __shfl(alpha, (lane & 48) | ((lane >> 2) & 12) | r);
#pragma unroll
          for (int n = 0; n < 4; ++n)
#pragma unroll
            for (int r = 0; r < 4; ++r) O[n][r] *= aO[r];
        }

        float ts = 0.f;
#pragma unroll
        for (int cb = 0; cb < 4; ++cb)
#pragma unroll
          for (int r = 0; r < 4; ++r) {
            float pv = exp2f(st[cb][r] - mcur);
            st[cb][r] = pv;
            ts += pv;
          }
        ts += __shfl_xor(ts, 16);
        ts += __shfl_xor(ts, 32);
        l_reg += ts;

        ushort* pw = &Pl[wid][0];
#pragma unroll
        for (int cb = 0; cb < 4; ++cb) {
          int g = ((cb * 2 + (lg >> 1)) ^ (lr & 7)) << 3;
          int idx = lr * 64 + g + ((lg & 1) * 4);
          *(uint32_t*)&pw[idx] = pack2t(st[cb][0], st[cb][1]);
          *(uint32_t*)&pw[idx + 2] = pack2t(st[cb][2], st[cb][3]);
        }

        const ushort* vt = Vt[t & 1];
#pragma unroll
        for (int kk = 0; kk < 2; ++kk) {
          bf16x8 pa = ld_frag(&pw[swz(lr, kk * 4 + lg)]);
#pragma unroll
          for (int n = 0; n < 4; ++n) {
            bf16x8 vfr = ld_frag(&vt[swz(n * 16 + lr, kk * 4 + lg)]);
            O[n] = __builtin_amdgcn_mfma_f32_16x16x32_bf16(pa, vfr, O[n], 0, 0, 0);
          }
        }
      }
      __syncthreads();  // protects dbuf rotation
    }

    // ---- merge parities (wk=1 -> LDS, wk=0 combines & writes) ----
    float* mrg = (float*)&Kl[0][0];         // 16KB scratch, loop is done with Kl
    float* mw = mrg + wq * 1088;            // per-wq: 1024 O + 16 m + 16 l
    if (wk == 1) {
#pragma unroll
      for (int n = 0; n < 4; ++n)
#pragma unroll
        for (int r = 0; r < 4; ++r)
          mw[(lg * 4 + r) * 64 + n * 16 + lr] = O[n][r];
      if (lg == 0) {
        mw[1024 + lr] = m_reg;
        mw[1040 + lr] = l_reg;
      }
    }
    __syncthreads();
    if (wk == 0) {
      float mB = mw[1024 + lr], lB = mw[1040 + lr];
      float mS = fmaxf(m_reg, mB);
      float alpha = exp2f(m_reg - mS), beta = exp2f(mB - mS);
      float lS = l_reg * alpha + lB * beta;
      float linv = 1.f / lS;
      float aO[4], bO[4], iO[4];
#pragma unroll
      for (int r = 0; r < 4; ++r) {
        int src = (lane & 48) | ((lane >> 2) & 12) | r;
        aO[r] = __shfl(alpha, src);
        bO[r] = __shfl(beta, src);
        iO[r] = __shfl(linv, src);
      }
#pragma unroll
      for (int r = 0; r < 4; ++r) {
        size_t row = (size_t)b * 2048 + q0w + lg * 4 + r;
#pragma unroll
        for (int n = 0; n < 4; ++n) {
          float ob = mw[(lg * 4 + r) * 64 + n * 16 + lr];
          float val = (O[n][r] * aO[r] + ob * bO[r]) * iO[r];
          Cx[row * 1024 + h * 64 + n * 16 + lr] = f2bf(val);
        }
      }
    }
    __syncthreads();  // before next segment re-stages Kl
  }
}

// ---------------------------------------------------------------------------
extern "C" void kernel_launch(void* const* d_in, const int* in_sizes, int n_in,
                              void* d_out, int out_size, void* d_ws, size_t ws_size,
                              hipStream_t stream) {
  const float* query = (const float*)d_in[0];
  const float* key_i = (const float*)d_in[1];
  const float* value = (const float*)d_in[2];
  // d_in[3] = mask: known causal (tril), exploited structurally.
  const float* Wq = (const float*)d_in[4];
  const float* bq = (const float*)d_in[5];
  const float* Wk = (const float*)d_in[6];
  const float* bk = (const float*)d_in[7];
  const float* Wv = (const float*)d_in[8];
  const float* bv = (const float*)d_in[9];
  const float* Wo = (const float*)d_in[10];
  const float* bo = (const float*)d_in[11];
  float* out = (float*)d_out;

  const size_t MD = (size_t)4096 * 1024;
  const size_t DD = (size_t)1024 * 1024;
  ushort* qbf = (ushort*)d_ws;
  ushort* kbf = qbf + MD;
  ushort* vbf = kbf + MD;
  ushort* Wqb = vbf + MD;
  ushort* Wkb = Wqb + DD;
  ushort* Wvb = Wkb + DD;
  ushort* Wob = Wvb + DD;
  ushort* Qb = Wob + DD;
  ushort* Kb = Qb + MD;
  ushort* Vb = Kb + MD;
  ushort* Cx = Vb + MD;

  cvt_all<<<2048, 256, 0, stream>>>(query, key_i, value, Wq, Wk, Wv, Wo,
                                    qbf, kbf, vbf, Wqb, Wkb, Wvb, Wob);

  // fused q/k/v projections: 8x32x3 = 768 blocks x 512 thr (3/CU, 24 waves/CU)
  gemm8<128, true, true><<<dim3(8, 32, 3), 512, 0, stream>>>(
      qbf, kbf, vbf, Wqb, Wkb, Wvb, bq, bk, bv, Qb, Kb, Vb, 1024, 1024);

  // attention: 32 bh x 32 pairs = 1024 blocks x 256 thr (4/CU, 16 waves/CU)
  attn_kernel<<<dim3(32, 32), 256, 0, stream>>>(Qb, Kb, Vb, Cx);

  // out projection: 16x32 = 512 blocks x 512 thr (2/CU, 16 waves/CU)
  gemm8<64, false, false><<<dim3(16, 32, 1), 512, 0, stream>>>(
      Cx, Cx, Cx, Wob, Wob, Wob, bo, bo, bo, out, out, out, 1024, 1024);
}